// Round 9
// baseline (491.721 us; speedup 1.0000x reference)
//
#include <hip/hip_runtime.h>

typedef __attribute__((ext_vector_type(4))) float f32x4;
typedef __attribute__((ext_vector_type(16))) float f32x16;
typedef __attribute__((ext_vector_type(4))) unsigned short u16x4;
typedef __attribute__((ext_vector_type(4))) int i32x4;
typedef __attribute__((ext_vector_type(8))) __bf16 bf16x8;

union FragAB {
  u16x4 u[2];
  i32x4 v;
  bf16x8 f;
};

static __device__ __forceinline__ unsigned short f2bf(float x) {
  union { float f; unsigned u; } v;
  v.f = x;
  unsigned r = v.u + 0x7FFFu + ((v.u >> 16) & 1u);  // round-to-nearest-even
  return (unsigned short)(r >> 16);
}

#define NN 8192

// ---------- kernel 1: prep (unchanged, verified) ----------
__global__ __launch_bounds__(256) void k_prep(
    const int* __restrict__ adj, const float* __restrict__ V,
    const float* __restrict__ w1, const float* __restrict__ w2,
    const float* __restrict__ w3, const float* __restrict__ bias,
    unsigned char* __restrict__ adj2b, unsigned short* __restrict__ Vbp,
    unsigned short* __restrict__ Wbp, float* __restrict__ out) {
  int t = blockIdx.x * 256 + threadIdx.x;
  int nT = gridDim.x * 256;
  for (int g = t; g < 16777216; g += nT) {
    i32x4 a = *(const i32x4*)(adj + (size_t)g * 4);
    adj2b[g] = (unsigned char)((a.x & 3) | ((a.y & 3) << 2) |
                               ((a.z & 3) << 4) | ((a.w & 3) << 6));
  }
  for (int g = t; g < 524288; g += nT) {
    int f = g * 4;
    int row = f >> 8, kcol = f & 255;
    f32x4 x = *(const f32x4*)(V + (size_t)f);
    u16x4 h;
    h.x = f2bf(x.x); h.y = f2bf(x.y); h.z = f2bf(x.z); h.w = f2bf(x.w);
    *(u16x4*)(Vbp + (size_t)(kcol >> 3) * 65536 + (size_t)row * 8 + (kcol & 7)) = h;
  }
  for (int e = t; e < 65536; e += nT) {
    int k = e >> 8, n = e & 255;
    Wbp[(size_t)(k >> 3) * 6144 + (size_t)(0 * 256 + n) * 8 + (k & 7)] = f2bf(w1[e]);
  }
  for (int e = t; e < 65536; e += nT) {
    int k = e >> 8, n = e & 255;
    Wbp[(size_t)(k >> 3) * 6144 + (size_t)(1 * 256 + n) * 8 + (k & 7)] = f2bf(w2[e]);
  }
  for (int e = t; e < 65536; e += nT) {
    int k = e >> 8, n = e & 255;
    Wbp[(size_t)(k >> 3) * 6144 + (size_t)(2 * 256 + n) * 8 + (k & 7)] = f2bf(w3[e]);
  }
  for (int g = t; g < 524288; g += nT) {
    *(f32x4*)(out + (size_t)g * 4) = *(const f32x4*)(bias + ((g * 4) & 255));
  }
}

// ---------- kernel 2: Bp = (V @ Wcat)^T, reg GEMM (unchanged, verified) ----------
// Bp element (ty, n, j) at  ty*2097152 + (j>>4)*4096 + n*16 + (j&15).
__global__ __launch_bounds__(256) void k_transform(
    const unsigned short* __restrict__ Vbp, const unsigned short* __restrict__ Wbp,
    unsigned short* __restrict__ Bp) {
  int bx = blockIdx.x;
  int rb = bx & 127, nb = bx >> 7;
  int tid = threadIdx.x, lane = tid & 63;
  int wv = tid >> 6;
  int wr = wv >> 1, wc = wv & 1;
  int q = lane >> 4, l16 = lane & 15;

  f32x4 acc[2][4];
#pragma unroll
  for (int i = 0; i < 2; i++)
#pragma unroll
    for (int j = 0; j < 4; j++) acc[i][j] = (f32x4)0.0f;

  int r0 = rb * 64 + wr * 32 + l16;
  int n0 = nb * 128 + wc * 64 + l16;
  const unsigned short* av = Vbp + (size_t)q * 65536 + (size_t)r0 * 8;
  const unsigned short* bv = Wbp + (size_t)q * 6144 + (size_t)n0 * 8;

#pragma unroll 2
  for (int kk = 0; kk < 256; kk += 32) {
    FragAB af[2], bf[4];
#pragma unroll
    for (int mt = 0; mt < 2; mt++)
      af[mt].v = *(const i32x4*)(av + (size_t)(kk >> 3) * 65536 + mt * 128);
#pragma unroll
    for (int nt = 0; nt < 4; nt++)
      bf[nt].v = *(const i32x4*)(bv + (size_t)(kk >> 3) * 6144 + nt * 128);
#pragma unroll
    for (int mt = 0; mt < 2; mt++)
#pragma unroll
      for (int nt = 0; nt < 4; nt++)
        acc[mt][nt] = __builtin_amdgcn_mfma_f32_16x16x32_bf16(
            af[mt].f, bf[nt].f, acc[mt][nt], 0, 0, 0);
  }
#pragma unroll
  for (int mt = 0; mt < 2; mt++)
#pragma unroll
    for (int nt = 0; nt < 4; nt++) {
      int n = n0 + nt * 16;
      int ty = n >> 8, nn = n & 255;
      int j0 = rb * 64 + wr * 32 + mt * 16 + q * 4;
      u16x4 hv;
      hv.x = f2bf(acc[mt][nt].x);
      hv.y = f2bf(acc[mt][nt].y);
      hv.z = f2bf(acc[mt][nt].z);
      hv.w = f2bf(acc[mt][nt].w);
      size_t idx = (size_t)ty * 2097152 + (size_t)(j0 >> 4) * 4096 + nn * 16 + (j0 & 15);
      *(u16x4*)(Bp + idx) = hv;
    }
}

// ---------- kernel 3: out += sum_k (adj==k) @ H_k ----------
// v10 = v9 geometry (wave 64x128, mt=2/nt=4, no LDS/barriers) with:
//  (1) 4-slot/3-ahead chunk rotation -> ~350+ cyc load cover (v9: 2-ahead),
//  (2) SWAR mask build: one xor/or/not/and pass yields all 16 match bits,
//      per-dword value = (b0 + b1<<16) * 0x3F80 (no per-elem compares) --
//      bit-identical to the verified cmp/select path,
//  (3) 2-step pairs: ptr bumps + adj ull loads per 64-k (halved bookkeeping).
// Grid 64 rb x 8 ks = 512 blocks (2/CU); ks = bx&7 -> per-XCD L2 k-slice.
__global__ __launch_bounds__(256, 2) void k_agg(const unsigned* __restrict__ adj2,
                                                const unsigned short* __restrict__ Bp,
                                                float* __restrict__ out) {
  int bx = blockIdx.x;
  int ks = bx & 7, rb = bx >> 3;
  int tid = threadIdx.x, lane = tid & 63;
  int wv = tid >> 6;
  int wm = wv >> 1, wn = wv & 1;  // wm: 64-row slab, wn: 128-col slab
  int q = lane >> 5, l32 = lane & 31;
  int qsh = q << 4;

  f32x16 acc[2][4];
#pragma unroll
  for (int mt = 0; mt < 2; mt++)
#pragma unroll
    for (int nt = 0; nt < 4; nt++) acc[mt][nt] = (f32x16)0.0f;

  // adj2 rows for this lane's two 32-row MFMA slabs (verified addressing)
  int r0 = rb * 128 + wm * 64 + l32;
  const unsigned* ap0 = adj2 + (size_t)r0 * 512 + ks * 64;
  const unsigned* ap1 = ap0 + 32 * 512;

  // 6 B-pointers [ty][kh]; elem = ty*2097152 + (ks*64+kh)*4096 + n*16 + q*8
  int nbase = (wn * 128 + l32) * 16 + q * 8;
  const unsigned short* bb[3][2];
#pragma unroll
  for (int ty = 0; ty < 3; ty++)
#pragma unroll
    for (int kh = 0; kh < 2; kh++)
      bb[ty][kh] = Bp + (size_t)ty * 2097152 + ((size_t)ks * 64 + kh) * 4096 + nbase;

  FragAB ch[4][4];  // rotating chunk buffers (slots 0..3), 3-ahead issue

#define AGG_ISSUE(SLOT, TY, KH, OFF)                                           \
  {                                                                            \
    _Pragma("unroll") for (int nt = 0; nt < 4; nt++)                           \
        ch[SLOT][nt].v = *(const i32x4*)(bb[TY][KH] + (OFF) + nt * 512);       \
  }

  // SWAR A-build + 8 MFMAs. Match bits: m = ~(x|(x>>1)) & 0x5555... where
  // x = codes ^ replicate(ty); bit 2j set iff code j == ty. For output dword
  // d: b0 = bit 4d (elem 2d), b1 = bit 4d+2 (elem 2d+1);
  // value = (b0 + (b1<<16)) * 0x3F80 = b0*0x3F80 | b1*0x3F800000.
#define AGG_COMPUTE(SLOT, TY, HI, C0, C1)                                      \
  {                                                                            \
    const unsigned pat = (unsigned)((TY + 1) * 0x55555555u);                   \
    unsigned x0 = ((unsigned)(HI ? (C0 >> 32) : C0)) ^ pat;                    \
    unsigned x1 = ((unsigned)(HI ? (C1 >> 32) : C1)) ^ pat;                    \
    unsigned mq0 = ((~(x0 | (x0 >> 1))) & 0x55555555u) >> qsh;                 \
    unsigned mq1 = ((~(x1 | (x1 >> 1))) & 0x55555555u) >> qsh;                 \
    FragAB A0, A1;                                                             \
    _Pragma("unroll") for (int d = 0; d < 4; d++) {                            \
      unsigned t0 = mq0 >> (4 * d), t1 = mq1 >> (4 * d);                       \
      A0.v[d] = (int)(((t0 & 1u) + ((t0 & 4u) << 14)) * 0x3F80u);              \
      A1.v[d] = (int)(((t1 & 1u) + ((t1 & 4u) << 14)) * 0x3F80u);              \
    }                                                                          \
    _Pragma("unroll") for (int nt = 0; nt < 4; nt++) {                         \
      acc[0][nt] = __builtin_amdgcn_mfma_f32_32x32x16_bf16(                    \
          A0.f, ch[SLOT][nt].f, acc[0][nt], 0, 0, 0);                          \
      acc[1][nt] = __builtin_amdgcn_mfma_f32_32x32x16_bf16(                    \
          A1.f, ch[SLOT][nt].f, acc[1][nt], 0, 0, 0);                          \
    }                                                                          \
  }

  // prologue: codes for steps 0,1; issue step-0 chunks (0,0),(1,0),(2,0)
  unsigned long long cA0 = *(const unsigned long long*)(ap0);
  unsigned long long cA1 = *(const unsigned long long*)(ap1);
  unsigned long long cB0 = *(const unsigned long long*)(ap0 + 2);
  unsigned long long cB1 = *(const unsigned long long*)(ap1 + 2);
  AGG_ISSUE(0, 0, 0, 0)
  AGG_ISSUE(1, 1, 0, 0)
  AGG_ISSUE(2, 2, 0, 0)

  for (int p = 0; p < 16; ++p) {  // 16 pairs x 2 steps (BK=32 each)
    unsigned long long nA0 = 0, nA1 = 0, nB0 = 0, nB1 = 0;
    if (p < 15) {  // next pair's codes
      nA0 = *(const unsigned long long*)(ap0 + 4 * p + 4);
      nA1 = *(const unsigned long long*)(ap1 + 4 * p + 4);
      nB0 = *(const unsigned long long*)(ap0 + 4 * p + 6);
      nB1 = *(const unsigned long long*)(ap1 + 4 * p + 6);
    }
    // stepA (cur offset 0; next step at +8192 elems)
    AGG_COMPUTE(0, 0, 0, cA0, cA1) AGG_ISSUE(3, 0, 1, 0)
    AGG_COMPUTE(1, 1, 0, cA0, cA1) AGG_ISSUE(0, 1, 1, 0)
    AGG_COMPUTE(2, 2, 0, cA0, cA1) AGG_ISSUE(1, 2, 1, 0)
    AGG_COMPUTE(3, 0, 1, cA0, cA1) AGG_ISSUE(2, 0, 0, 8192)
    AGG_COMPUTE(0, 1, 1, cA0, cA1) AGG_ISSUE(3, 1, 0, 8192)
    AGG_COMPUTE(1, 2, 1, cA0, cA1) AGG_ISSUE(0, 2, 0, 8192)
    // stepB (cur offset 8192; next pair at +16384 elems)
    AGG_COMPUTE(2, 0, 0, cB0, cB1) AGG_ISSUE(1, 0, 1, 8192)
    AGG_COMPUTE(3, 1, 0, cB0, cB1) AGG_ISSUE(2, 1, 1, 8192)
    AGG_COMPUTE(0, 2, 0, cB0, cB1) AGG_ISSUE(3, 2, 1, 8192)
    AGG_COMPUTE(1, 0, 1, cB0, cB1)
    if (p < 15) { AGG_ISSUE(0, 0, 0, 16384) }
    AGG_COMPUTE(2, 1, 1, cB0, cB1)
    if (p < 15) { AGG_ISSUE(1, 1, 0, 16384) }
    AGG_COMPUTE(3, 2, 1, cB0, cB1)
    if (p < 15) { AGG_ISSUE(2, 2, 0, 16384) }
#pragma unroll
    for (int ty = 0; ty < 3; ty++)
#pragma unroll
      for (int kh = 0; kh < 2; kh++) bb[ty][kh] += 16384;
    cA0 = nA0; cA1 = nA1; cB0 = nB0; cB1 = nB1;
  }
#undef AGG_ISSUE
#undef AGG_COMPUTE
  // epilogue: C/D 32x32 layout col=lane&31, row=(reg&3)+8*(reg>>2)+4*q
#pragma unroll
  for (int mt = 0; mt < 2; mt++)
#pragma unroll
    for (int nt = 0; nt < 4; nt++) {
      int col = wn * 128 + nt * 32 + l32;
      int rowb = rb * 128 + wm * 64 + mt * 32 + 4 * q;
#pragma unroll
      for (int r = 0; r < 16; r++) {
        int row = rowb + (r & 3) + 8 * (r >> 2);
        atomicAdd(out + (size_t)row * 256 + col, acc[mt][nt][r]);
      }
    }
}

extern "C" void kernel_launch(void* const* d_in, const int* in_sizes, int n_in,
                              void* d_out, int out_size, void* d_ws,
                              size_t ws_size, hipStream_t stream) {
  const float* V = (const float*)d_in[0];
  const int* adj = (const int*)d_in[1];
  const float* w1 = (const float*)d_in[2];
  const float* w2 = (const float*)d_in[3];
  const float* w3 = (const float*)d_in[4];
  const float* bias = (const float*)d_in[5];
  float* out = (float*)d_out;
  // workspace layout:
  unsigned short* Bp = (unsigned short*)d_ws;                       // 12.58 MB @ 0
  unsigned char* adj2b = (unsigned char*)d_ws + 0xC00000;           // 16 MB
  unsigned short* Vbp = (unsigned short*)((char*)d_ws + 0x1C00000); // 4 MB
  unsigned short* Wbp = (unsigned short*)((char*)d_ws + 0x2000000); // 0.375 MB
  // total required: 0x2060000 = 33.9 MB

  k_prep<<<dim3(2048), dim3(256), 0, stream>>>(adj, V, w1, w2, w3, bias, adj2b,
                                               Vbp, Wbp, out);
  k_transform<<<dim3(768), dim3(256), 0, stream>>>(Vbp, Wbp, Bp);
  k_agg<<<dim3(512), dim3(256), 0, stream>>>((const unsigned*)adj2b, Bp, out);
}